// Round 1
// baseline (1287.676 us; speedup 1.0000x reference)
//
#include <hip/hip_runtime.h>
#include <math.h>

#define Bq 4
#define Nq 512
#define Dq 128

// hyperparameters
#define C_UNTANH   3.0f
#define C_BSCALE   1.8477590650225735f   // sqrt(2+sqrt(2))
#define C_INVSQRTD 0.08838834764831845f  // 1/sqrt(128)
#define C_WD       1e-4f
#define C_MOM      0.9f
#define C_LR       0.01f
#define C_WSCALE   4.0f

// ---------------- forward: pred/key/query = buntanh(state @ W_i) ----------------
__global__ __launch_bounds__(256) void k_fwd(const float* __restrict__ state,
    const float* __restrict__ w1, const float* __restrict__ w2, const float* __restrict__ w3,
    float* __restrict__ pred, float* __restrict__ keyv, float* __restrict__ qry) {
  int bn = blockIdx.x;
  int t = threadIdx.x;
  int k = t & 127;
  int half = t >> 7;  // 0/1 -> j in [0,64) or [64,128)
  __shared__ float xs[Dq];
  __shared__ float ps[256];
  if (t < Dq) xs[t] = state[bn * Dq + t];
  __syncthreads();
  const float* Ws[3] = {w1, w2, w3};
  float* dsts[3] = {pred, keyv, qry};  // w1->prediction, w2->keys, w3->queries
  for (int p = 0; p < 3; p++) {
    const float* W = Ws[p] + (size_t)bn * Dq * Dq + (size_t)half * 64 * Dq;
    float acc = 0.f;
#pragma unroll 16
    for (int j = 0; j < 64; j++) acc += xs[half * 64 + j] * W[j * Dq + k];
    ps[t] = acc;
    __syncthreads();
    if (t < Dq) {
      float r = ps[t] + ps[t + 128];
      r = C_UNTANH * tanhf(r / C_UNTANH) * C_BSCALE;
      dsts[p][bn * Dq + t] = r;
    }
    __syncthreads();
  }
}

// ---------------- raw_S = Q K^T / sqrt(D), with per-b sum of squares ----------------
__global__ __launch_bounds__(256) void k_qk(const float* __restrict__ qry,
    const float* __restrict__ keyv, float* __restrict__ rawS, double* __restrict__ part) {
  __shared__ float Qs[16][Dq + 1];
  __shared__ float Ks[16][Dq + 1];
  __shared__ double red[256];
  int b = blockIdx.z, n0 = blockIdx.x * 16, m0 = blockIdx.y * 16;
  int t = threadIdx.x;
#pragma unroll
  for (int i = 0; i < 8; i++) {
    int idx = i * 256 + t;
    int r = idx >> 7, c = idx & 127;
    Qs[r][c] = qry[((size_t)b * Nq + n0 + r) * Dq + c];
    Ks[r][c] = keyv[((size_t)b * Nq + m0 + r) * Dq + c];
  }
  __syncthreads();
  int tn = t >> 4, tm = t & 15;
  float a = 0.f;
#pragma unroll 16
  for (int d = 0; d < Dq; d++) a += Qs[tn][d] * Ks[tm][d];
  a *= C_INVSQRTD;
  rawS[((size_t)b * Nq + n0 + tn) * Nq + m0 + tm] = a;
  red[t] = (double)a * (double)a;
  __syncthreads();
  for (int s = 128; s > 0; s >>= 1) { if (t < s) red[t] += red[t + s]; __syncthreads(); }
  if (t == 0) part[(size_t)b * 1024 + blockIdx.y * 32 + blockIdx.x] = red[0];
}

__global__ __launch_bounds__(256) void k_acc(const double* __restrict__ part, double* __restrict__ acc) {
  int b = blockIdx.x, t = threadIdx.x;
  double s = 0.0;
  for (int i = t; i < 1024; i += 256) s += part[(size_t)b * 1024 + i];
  __shared__ double red[256];
  red[t] = s;
  __syncthreads();
  for (int k = 128; k > 0; k >>= 1) { if (t < k) red[t] += red[t + k]; __syncthreads(); }
  if (t == 0) acc[b] = red[0];
}

// ---------------- A_ema_new = 0.9*A_ema + 0.1*rms_norm(rawS)  (in-place on rawS) ----------------
__global__ __launch_bounds__(256) void k_ema(float* __restrict__ A, const float* __restrict__ A_ema,
    const double* __restrict__ acc, const int* __restrict__ stepc, float* __restrict__ outA) {
  int idx = blockIdx.x * 256 + threadIdx.x;
  if (idx >= Bq * Nq * Nq) return;
  int b = idx / (Nq * Nq);
  float mean = (float)(acc[b] / (double)(Nq * Nq));
  float rs = 1.0f / sqrtf(mean + 1e-8f);
  float val = A[idx] * rs;
  float res = (stepc[0] == 1) ? val : 0.9f * A_ema[idx] + 0.1f * val;
  outA[idx] = res;
  A[idx] = res;
}

// ---------------- sinkhorn phases (fp64 sums for stability) ----------------
__global__ __launch_bounds__(256) void k_row(float* __restrict__ A) {
  int bn = blockIdx.x, t = threadIdx.x;
  float* row = A + (size_t)bn * Nq;
  float v0 = row[t], v1 = row[t + 256];
  __shared__ double red[256];
  red[t] = (double)v0 + (double)v1;
  __syncthreads();
  for (int s = 128; s > 0; s >>= 1) { if (t < s) red[t] += red[t + s]; __syncthreads(); }
  double den = red[0] + 1e-6;
  row[t] = (float)((double)v0 / den);
  row[t + 256] = (float)((double)v1 / den);
}

__global__ __launch_bounds__(256) void k_col(float* __restrict__ A) {
  int blk = blockIdx.x, t = threadIdx.x;
  int b = blk >> 9, m = blk & 511;
  float* base = A + (size_t)b * Nq * Nq + m;
  float v0 = base[(size_t)t * Nq], v1 = base[(size_t)(t + 256) * Nq];
  __shared__ double red[256];
  red[t] = (double)v0 + (double)v1;
  __syncthreads();
  for (int s = 128; s > 0; s >>= 1) { if (t < s) red[t] += red[t + s]; __syncthreads(); }
  double den = red[0] + 1e-6;
  base[(size_t)t * Nq] = (float)((double)v0 / den);
  base[(size_t)(t + 256) * Nq] = (float)((double)v1 / den);
}

__global__ __launch_bounds__(256) void k_sparse(float* __restrict__ A) {
  int idx = blockIdx.x * 256 + threadIdx.x;
  if (idx >= Bq * Nq * Nq) return;
  float v = A[idx];
  A[idx] = (v > 0.0009765625f) ? v : 0.0f;  // 0.5/N
}

// ---------------- target = A @ output ; rows 0,1 = env ----------------
__global__ __launch_bounds__(128) void k_target(const float* __restrict__ A,
    const float* __restrict__ output, const float* __restrict__ eye_env,
    const float* __restrict__ stomach_env, float* __restrict__ out_state) {
  int bn = blockIdx.x, t = threadIdx.x;
  int b = bn >> 9, n = bn & 511;
  float tg;
  if (n == 0) {
    tg = eye_env[b * Dq + t];
  } else if (n == 1) {
    tg = stomach_env[b * Dq + t];
  } else {
    const float* Arow = A + (size_t)bn * Nq;
    const float* ob = output + (size_t)b * Nq * Dq;
    __shared__ float as[128];
    float acc = 0.f;
    for (int m0 = 0; m0 < Nq; m0 += 128) {
      __syncthreads();
      as[t] = Arow[m0 + t];
      __syncthreads();
#pragma unroll 16
      for (int m = 0; m < 128; m++) acc += as[m] * ob[(size_t)(m0 + m) * Dq + t];
    }
    tg = acc;
  }
  out_state[(size_t)bn * Dq + t] = tg;
}

// ---------------- error signals + softmax/plasticity + mean(state^2) ----------------
__device__ __forceinline__ void softmax_plast(float e, const float* __restrict__ eb,
    float* __restrict__ pl, int base, int t, float* red) {
  red[t] = e;
  __syncthreads();
  for (int s = 64; s > 0; s >>= 1) { if (t < s) red[t] = fmaxf(red[t], red[t + s]); __syncthreads(); }
  float mx = red[0];
  __syncthreads();
  float ex = expf(e - mx);
  red[t] = ex;
  __syncthreads();
  for (int s = 64; s > 0; s >>= 1) { if (t < s) red[t] += red[t + s]; __syncthreads(); }
  float Ec = ex / red[0];
  __syncthreads();
  float En = eb[base] * 0.99f + 0.01f * Ec;  // EMA_SPEED = 0.01
  float adv = Ec - En;
  float x = adv * 4.0f;                      // REW_SENS
  pl[base] = 1.0f + x / sqrtf(x * x + 1e-8f);
}

__global__ __launch_bounds__(128) void k_err(const float* __restrict__ pred,
    const float* __restrict__ qry, const float* __restrict__ keyv,
    const float* __restrict__ target, const float* __restrict__ state,
    const float* __restrict__ eb1, const float* __restrict__ eb2, const float* __restrict__ eb3,
    float* __restrict__ err1, float* __restrict__ err2, float* __restrict__ err3,
    float* __restrict__ pl1, float* __restrict__ pl2, float* __restrict__ pl3,
    float* __restrict__ msn) {
  int bn = blockIdx.x, t = threadIdx.x;
  int base = bn * Dq + t;
  float pr = pred[base], qv = qry[base], kv = keyv[base], tg = target[base];
  float e1b = pr - tg;
  float e2 = kv - e1b;
  float e3 = qv - e2;
  float e1 = pr - (tg + e3);
  err1[base] = e1; err2[base] = e2; err3[base] = e3;
  __shared__ float red[128];
  float st = state[base];
  red[t] = st * st;
  __syncthreads();
  for (int s = 64; s > 0; s >>= 1) { if (t < s) red[t] += red[t + s]; __syncthreads(); }
  if (t == 0) msn[bn] = red[0] / (float)Dq;
  __syncthreads();
  softmax_plast(e1, eb1, pl1, base, t, red);
  softmax_plast(e2, eb2, pl2, base, t, red);
  softmax_plast(e3, eb3, pl3, base, t, red);
}

// ---------------- weight update (noise omitted: noisy == state) ----------------
__device__ __forceinline__ float stepw(float w, float g, float c, float st, float mk, double* ssq) {
  float grad = (c * st - C_WD * w) * mk;     // (plast*lg1 - WD*W)*mask
  float gn = C_MOM * g + (1.0f - C_MOM) * grad;
  float wn = w + C_LR * gn;
  *ssq += (double)wn * (double)wn;
  return wn;
}

__global__ __launch_bounds__(256) void k_step(const float* __restrict__ W, const float* __restrict__ G,
    const float* __restrict__ err, const float* __restrict__ pl, const float* __restrict__ state,
    const float* __restrict__ msn, const int* __restrict__ stepc, float* __restrict__ outW) {
  int bn = blockIdx.x, t = threadIdx.x;
  __shared__ __align__(16) float Wn[Dq * Dq];
  __shared__ __align__(16) float ers[Dq];
  __shared__ __align__(16) float pls[Dq];
  __shared__ __align__(16) float sts[Dq];
  __shared__ __align__(16) float msk[Dq];
  __shared__ double red[256];
  if (t < Dq) {
    ers[t] = err[bn * Dq + t];
    pls[t] = pl[bn * Dq + t];
    sts[t] = state[bn * Dq + t];
    float center = fmodf((float)stepc[0] * 1.0f, 128.0f);  // (step*SPEED) % D
    float d = fabsf((float)t - center);
    d = fminf(d, 128.0f - d);
    msk[t] = expf(-(d * d) * (1.0f / 32.0f));  // 2*WIDTH^2 = 32
  }
  float msnv = msn[bn];
  __syncthreads();
  const float4* W4 = (const float4*)(W + (size_t)bn * Dq * Dq);
  const float4* G4 = (const float4*)(G + (size_t)bn * Dq * Dq);
  float4* Wn4 = (float4*)Wn;
  double ssq = 0.0;
#pragma unroll
  for (int i = 0; i < 16; i++) {
    int f4 = i * 256 + t;
    int p = f4 >> 5;
    float4 w4v = W4[f4];
    float4 g4v = G4[f4];
    float4 st4 = ((const float4*)sts)[f4 & 31];
    float4 mk4 = ((const float4*)msk)[f4 & 31];
    float ep = ers[p];
    float denom = sqrtf(ep * ep * msnv + 1e-8f);
    float c = -pls[p] * ep / denom;  // lg1 = -ep*st_q/denom ; grad_in = plast*lg1
    float4 o;
    o.x = stepw(w4v.x, g4v.x, c, st4.x, mk4.x, &ssq);
    o.y = stepw(w4v.y, g4v.y, c, st4.y, mk4.y, &ssq);
    o.z = stepw(w4v.z, g4v.z, c, st4.z, mk4.z, &ssq);
    o.w = stepw(w4v.w, g4v.w, c, st4.w, mk4.w, &ssq);
    Wn4[f4] = o;
  }
  red[t] = ssq;
  __syncthreads();
  for (int s = 128; s > 0; s >>= 1) { if (t < s) red[t] += red[t + s]; __syncthreads(); }
  float mean = (float)(red[0] / (double)(Dq * Dq));
  float scale = C_WSCALE / sqrtf(mean + 1e-8f);
  float4* out4 = (float4*)(outW + (size_t)bn * Dq * Dq);
#pragma unroll
  for (int i = 0; i < 16; i++) {
    int f4 = i * 256 + t;
    float4 v = Wn4[f4];
    v.x *= scale; v.y *= scale; v.z *= scale; v.w *= scale;
    out4[f4] = v;
  }
}

extern "C" void kernel_launch(void* const* d_in, const int* in_sizes, int n_in,
                              void* d_out, int out_size, void* d_ws, size_t ws_size,
                              hipStream_t stream) {
  const float* state   = (const float*)d_in[0];
  const float* output  = (const float*)d_in[1];
  const float* A_ema   = (const float*)d_in[2];
  const float* w1      = (const float*)d_in[3];
  const float* w2      = (const float*)d_in[4];
  const float* w3      = (const float*)d_in[5];
  const float* g1      = (const float*)d_in[6];
  const float* g2      = (const float*)d_in[7];
  const float* g3      = (const float*)d_in[8];
  const float* eb1     = (const float*)d_in[9];
  const float* eb2     = (const float*)d_in[10];
  const float* eb3     = (const float*)d_in[11];
  const float* eye     = (const float*)d_in[12];
  const float* stomach = (const float*)d_in[13];
  const int*   stepc   = (const int*)d_in[14];

  float* out = (float*)d_out;
  float* o_state = out;                    // [B,N,D] 262144
  float* o_out   = out + 262144;           // prediction
  float* o_w1    = out + 524288;           // [B,N,D,D] 33554432
  float* o_w2    = o_w1 + 33554432;
  float* o_w3    = o_w2 + 33554432;
  float* o_A     = o_w3 + 33554432;        // [B,N,N] 1048576

  float* ws = (float*)d_ws;
  float* A    = ws;                 // 1048576 (rawS, then sinkhorn A)
  float* qry  = ws + 1048576;       // 262144
  float* keyv = ws + 1310720;       // 262144
  float* err1 = ws + 1572864;
  float* err2 = ws + 1835008;
  float* err3 = ws + 2097152;
  float* pl1  = ws + 2359296;
  float* pl2  = ws + 2621440;
  float* pl3  = ws + 2883584;
  float* msn  = ws + 3145728;       // 2048
  double* part = (double*)(ws + 3147776);  // 4096 doubles
  double* acc  = part + 4096;              // 4 doubles

  // forward (pred written straight into new_output region)
  k_fwd<<<Bq * Nq, 256, 0, stream>>>(state, w1, w2, w3, o_out, keyv, qry);
  // attention raw scores + per-b sumsq
  k_qk<<<dim3(32, 32, Bq), 256, 0, stream>>>(qry, keyv, A, part);
  k_acc<<<Bq, 256, 0, stream>>>(part, acc);
  // EMA (also writes A_ema_new output)
  k_ema<<<4096, 256, 0, stream>>>(A, A_ema, acc, stepc, o_A);
  // sinkhorn #1
  for (int it = 0; it < 5; it++) {
    k_row<<<Bq * Nq, 256, 0, stream>>>(A);
    k_col<<<Bq * Nq, 256, 0, stream>>>(A);
  }
  // sparsify
  k_sparse<<<4096, 256, 0, stream>>>(A);
  // sinkhorn #2
  for (int it = 0; it < 5; it++) {
    k_row<<<Bq * Nq, 256, 0, stream>>>(A);
    k_col<<<Bq * Nq, 256, 0, stream>>>(A);
  }
  // target (rows 0,1 = env; A rows 0,1 unused == zeroed)
  k_target<<<Bq * Nq, 128, 0, stream>>>(A, output, eye, stomach, o_state);
  // errors, softmax plasticity, mean(state^2)
  k_err<<<Bq * Nq, 128, 0, stream>>>(o_out, qry, keyv, o_state, state,
                                     eb1, eb2, eb3, err1, err2, err3, pl1, pl2, pl3, msn);
  // weight updates
  k_step<<<Bq * Nq, 256, 0, stream>>>(w1, g1, err1, pl1, state, msn, stepc, o_w1);
  k_step<<<Bq * Nq, 256, 0, stream>>>(w2, g2, err2, pl2, state, msn, stepc, o_w2);
  k_step<<<Bq * Nq, 256, 0, stream>>>(w3, g3, err3, pl3, state, msn, stepc, o_w3);
}